// Round 1
// baseline (109.513 us; speedup 1.0000x reference)
//
#include <hip/hip_runtime.h>

#define NN 8192
#define DD 64

typedef short bf16x8 __attribute__((ext_vector_type(8)));
typedef float f32x4 __attribute__((ext_vector_type(4)));

__device__ __forceinline__ unsigned short f2bf(float f) {
    unsigned int u = __float_as_uint(f);
    unsigned int r = (u + 0x7FFFu + ((u >> 16) & 1u)) >> 16;
    return (unsigned short)r;
}

// One block computes a 128x128 output tile.
// 256 threads = 4 waves arranged 2x2, each wave owns a 64x64 sub-tile
// (4x4 fragments of 16x16, mfma_f32_16x16x32_bf16, K=64 in 2 steps).
__global__ __launch_bounds__(256) void rips_kernel(const float* __restrict__ X,
                                                   float* __restrict__ out) {
    const int rowBase = blockIdx.y * 128;
    const int colBase = blockIdx.x * 128;
    const int tid  = threadIdx.x;
    const int lane = tid & 63;
    const int w    = tid >> 6;
    const int wr   = w >> 1;   // wave row (0..1)
    const int wc   = w & 1;    // wave col (0..1)

    __shared__ float rn[128];
    __shared__ float cn[128];

    // ---- Phase 1: fp32 squared norms of this tile's 128 rows and 128 cols ----
    {
        const int idx  = tid & 127;
        const int base = (tid < 128) ? rowBase : colBase;
        const float4* p = (const float4*)(X + (size_t)(base + idx) * DD);
        float acc = 0.0f;
        #pragma unroll
        for (int i = 0; i < 16; ++i) {
            float4 v = p[i];
            acc += v.x * v.x + v.y * v.y + v.z * v.z + v.w * v.w;
        }
        if (tid < 128) rn[idx] = acc;
        else           cn[idx] = acc;
    }
    __syncthreads();

    // ---- Phase 2: gram tile via bf16 MFMA, fragments straight from global ----
    f32x4 acc[4][4];
    #pragma unroll
    for (int m = 0; m < 4; ++m)
        #pragma unroll
        for (int n = 0; n < 4; ++n)
            acc[m][n] = (f32x4){0.f, 0.f, 0.f, 0.f};

    const int fr = lane & 15;   // fragment row (A) / col (B)
    const int kg = lane >> 4;   // k-group (0..3), 8 elems each

    #pragma unroll
    for (int kk = 0; kk < DD; kk += 32) {
        bf16x8 a[4], b[4];
        #pragma unroll
        for (int m = 0; m < 4; ++m) {
            const float* p = X + (size_t)(rowBase + wr * 64 + m * 16 + fr) * DD + kk + kg * 8;
            float4 lo = *(const float4*)p;
            float4 hi = *(const float4*)(p + 4);
            bf16x8 t;
            t[0] = (short)f2bf(lo.x); t[1] = (short)f2bf(lo.y);
            t[2] = (short)f2bf(lo.z); t[3] = (short)f2bf(lo.w);
            t[4] = (short)f2bf(hi.x); t[5] = (short)f2bf(hi.y);
            t[6] = (short)f2bf(hi.z); t[7] = (short)f2bf(hi.w);
            a[m] = t;
        }
        #pragma unroll
        for (int n = 0; n < 4; ++n) {
            const float* p = X + (size_t)(colBase + wc * 64 + n * 16 + fr) * DD + kk + kg * 8;
            float4 lo = *(const float4*)p;
            float4 hi = *(const float4*)(p + 4);
            bf16x8 t;
            t[0] = (short)f2bf(lo.x); t[1] = (short)f2bf(lo.y);
            t[2] = (short)f2bf(lo.z); t[3] = (short)f2bf(lo.w);
            t[4] = (short)f2bf(hi.x); t[5] = (short)f2bf(hi.y);
            t[6] = (short)f2bf(hi.z); t[7] = (short)f2bf(hi.w);
            b[n] = t;
        }
        #pragma unroll
        for (int m = 0; m < 4; ++m)
            #pragma unroll
            for (int n = 0; n < 4; ++n)
                acc[m][n] = __builtin_amdgcn_mfma_f32_16x16x32_bf16(a[m], b[n], acc[m][n], 0, 0, 0);
    }

    // ---- Epilogue: d = sqrt(max(rn + cn - 2*gram, 0)), diag forced to 0 ----
    // C/D layout (16x16x32): col = lane&15, row = (lane>>4)*4 + reg.
    #pragma unroll
    for (int m = 0; m < 4; ++m) {
        #pragma unroll
        for (int n = 0; n < 4; ++n) {
            #pragma unroll
            for (int r = 0; r < 4; ++r) {
                const int row_l = wr * 64 + m * 16 + kg * 4 + r;
                const int col_l = wc * 64 + n * 16 + fr;
                const float g  = acc[m][n][r];
                float sq = rn[row_l] + cn[col_l] - 2.0f * g;
                sq = fmaxf(sq, 0.0f);
                float dv = sqrtf(sq);
                const int grow = rowBase + row_l;
                const int gcol = colBase + col_l;
                if (grow == gcol) dv = 0.0f;
                out[(size_t)grow * NN + gcol] = dv;
            }
        }
    }
}

extern "C" void kernel_launch(void* const* d_in, const int* in_sizes, int n_in,
                              void* d_out, int out_size, void* d_ws, size_t ws_size,
                              hipStream_t stream) {
    const float* X = (const float*)d_in[0];
    float* out = (float*)d_out;
    dim3 grid(NN / 128, NN / 128, 1);
    rips_kernel<<<grid, dim3(256, 1, 1), 0, stream>>>(X, out);
}

// Round 2
// 63.572 us; speedup vs baseline: 1.7226x; 1.7226x over previous
//
#include <hip/hip_runtime.h>

#define NN 8192
#define DD 64

typedef short bf16x8 __attribute__((ext_vector_type(8)));
typedef float f32x4 __attribute__((ext_vector_type(4)));

__device__ __forceinline__ unsigned short f2bf(float f) {
    unsigned int u = __float_as_uint(f);
    unsigned int r = (u + 0x7FFFu + ((u >> 16) & 1u)) >> 16;
    return (unsigned short)r;
}

// ---- Setup: X fp32 -> bf16 (RNE) into ws, plus per-row squared norms ----
// 8 lanes per row, 8 elems per lane. 65536 threads total.
__global__ __launch_bounds__(256) void rips_setup(const float* __restrict__ X,
                                                  unsigned short* __restrict__ Xb,
                                                  float* __restrict__ norms) {
    const int t   = blockIdx.x * 256 + threadIdx.x;
    const int row = t >> 3;
    const int j   = t & 7;
    const float* p = X + (size_t)row * DD + j * 8;
    float4 lo = *(const float4*)p;
    float4 hi = *(const float4*)(p + 4);

    bf16x8 v;
    v[0] = (short)f2bf(lo.x); v[1] = (short)f2bf(lo.y);
    v[2] = (short)f2bf(lo.z); v[3] = (short)f2bf(lo.w);
    v[4] = (short)f2bf(hi.x); v[5] = (short)f2bf(hi.y);
    v[6] = (short)f2bf(hi.z); v[7] = (short)f2bf(hi.w);
    *(bf16x8*)(Xb + (size_t)row * DD + j * 8) = v;

    float acc = lo.x*lo.x + lo.y*lo.y + lo.z*lo.z + lo.w*lo.w
              + hi.x*hi.x + hi.y*hi.y + hi.z*hi.z + hi.w*hi.w;
    acc += __shfl_xor(acc, 1);
    acc += __shfl_xor(acc, 2);
    acc += __shfl_xor(acc, 4);
    if (j == 0) norms[row] = acc;
}

// ---- Main: 128x128 tile per 256-thread block (4 waves, 2x2 of 64x64). ----
// A operand = COLUMN fragments, B = ROW fragments, so the reg-indexed output
// dim (row=(lane>>4)*4+reg, verified m89) walks 4 consecutive COLUMNS ->
// float4 stores.
__global__ __launch_bounds__(256) void rips_main(const unsigned short* __restrict__ Xb,
                                                 const float* __restrict__ norms,
                                                 float* __restrict__ out) {
    const int rowBase = blockIdx.y * 128;
    const int colBase = blockIdx.x * 128;
    const int tid  = threadIdx.x;
    const int lane = tid & 63;
    const int w    = tid >> 6;
    const int wr   = w >> 1;
    const int wc   = w & 1;

    __shared__ float rn[128];
    __shared__ float cn[128];
    if (tid < 128) rn[tid]       = norms[rowBase + tid];
    else           cn[tid - 128] = norms[colBase + tid - 128];
    __syncthreads();

    const int fr = lane & 15;
    const int kg = lane >> 4;

    f32x4 acc[4][4];
    #pragma unroll
    for (int m = 0; m < 4; ++m)
        #pragma unroll
        for (int n = 0; n < 4; ++n)
            acc[m][n] = (f32x4){0.f, 0.f, 0.f, 0.f};

    #pragma unroll
    for (int kk = 0; kk < DD; kk += 32) {
        bf16x8 a[4], b[4];
        #pragma unroll
        for (int n = 0; n < 4; ++n)
            a[n] = *(const bf16x8*)(Xb + (size_t)(colBase + wc * 64 + n * 16 + fr) * DD + kk + kg * 8);
        #pragma unroll
        for (int m = 0; m < 4; ++m)
            b[m] = *(const bf16x8*)(Xb + (size_t)(rowBase + wr * 64 + m * 16 + fr) * DD + kk + kg * 8);
        #pragma unroll
        for (int m = 0; m < 4; ++m)
            #pragma unroll
            for (int n = 0; n < 4; ++n)
                acc[m][n] = __builtin_amdgcn_mfma_f32_16x16x32_bf16(a[n], b[m], acc[m][n], 0, 0, 0);
    }

    // Epilogue: lane holds row (fr) x 4 consecutive cols (kg*4 + 0..3).
    #pragma unroll
    for (int m = 0; m < 4; ++m) {
        const int row_l = wr * 64 + m * 16 + fr;
        const int grow  = rowBase + row_l;
        const float rnv = rn[row_l];
        #pragma unroll
        for (int n = 0; n < 4; ++n) {
            const int col0_l = wc * 64 + n * 16 + kg * 4;
            const int gcol0  = colBase + col0_l;
            const float4 cnv = *(const float4*)&cn[col0_l];
            float4 o;
            {
                float sq = fmaxf(rnv + cnv.x - 2.0f * acc[m][n][0], 0.0f);
                o.x = (grow == gcol0 + 0) ? 0.0f : sqrtf(sq);
                sq = fmaxf(rnv + cnv.y - 2.0f * acc[m][n][1], 0.0f);
                o.y = (grow == gcol0 + 1) ? 0.0f : sqrtf(sq);
                sq = fmaxf(rnv + cnv.z - 2.0f * acc[m][n][2], 0.0f);
                o.z = (grow == gcol0 + 2) ? 0.0f : sqrtf(sq);
                sq = fmaxf(rnv + cnv.w - 2.0f * acc[m][n][3], 0.0f);
                o.w = (grow == gcol0 + 3) ? 0.0f : sqrtf(sq);
            }
            *(float4*)(out + (size_t)grow * NN + gcol0) = o;
        }
    }
}

// ---- Fallback (R1 kernel): used only if ws_size is too small ----
__global__ __launch_bounds__(256) void rips_fallback(const float* __restrict__ X,
                                                     float* __restrict__ out) {
    const int rowBase = blockIdx.y * 128;
    const int colBase = blockIdx.x * 128;
    const int tid  = threadIdx.x;
    const int lane = tid & 63;
    const int w    = tid >> 6;
    const int wr   = w >> 1;
    const int wc   = w & 1;

    __shared__ float rn[128];
    __shared__ float cn[128];
    {
        const int idx  = tid & 127;
        const int base = (tid < 128) ? rowBase : colBase;
        const float4* p = (const float4*)(X + (size_t)(base + idx) * DD);
        float acc = 0.0f;
        #pragma unroll
        for (int i = 0; i < 16; ++i) {
            float4 v = p[i];
            acc += v.x * v.x + v.y * v.y + v.z * v.z + v.w * v.w;
        }
        if (tid < 128) rn[idx] = acc;
        else           cn[idx] = acc;
    }
    __syncthreads();

    f32x4 acc[4][4];
    #pragma unroll
    for (int m = 0; m < 4; ++m)
        #pragma unroll
        for (int n = 0; n < 4; ++n)
            acc[m][n] = (f32x4){0.f, 0.f, 0.f, 0.f};

    const int fr = lane & 15;
    const int kg = lane >> 4;

    #pragma unroll
    for (int kk = 0; kk < DD; kk += 32) {
        bf16x8 a[4], b[4];
        #pragma unroll
        for (int m = 0; m < 4; ++m) {
            const float* p = X + (size_t)(rowBase + wr * 64 + m * 16 + fr) * DD + kk + kg * 8;
            float4 lo = *(const float4*)p;
            float4 hi = *(const float4*)(p + 4);
            bf16x8 t;
            t[0] = (short)f2bf(lo.x); t[1] = (short)f2bf(lo.y);
            t[2] = (short)f2bf(lo.z); t[3] = (short)f2bf(lo.w);
            t[4] = (short)f2bf(hi.x); t[5] = (short)f2bf(hi.y);
            t[6] = (short)f2bf(hi.z); t[7] = (short)f2bf(hi.w);
            a[m] = t;
        }
        #pragma unroll
        for (int n = 0; n < 4; ++n) {
            const float* p = X + (size_t)(colBase + wc * 64 + n * 16 + fr) * DD + kk + kg * 8;
            float4 lo = *(const float4*)p;
            float4 hi = *(const float4*)(p + 4);
            bf16x8 t;
            t[0] = (short)f2bf(lo.x); t[1] = (short)f2bf(lo.y);
            t[2] = (short)f2bf(lo.z); t[3] = (short)f2bf(lo.w);
            t[4] = (short)f2bf(hi.x); t[5] = (short)f2bf(hi.y);
            t[6] = (short)f2bf(hi.z); t[7] = (short)f2bf(hi.w);
            b[n] = t;
        }
        #pragma unroll
        for (int m = 0; m < 4; ++m)
            #pragma unroll
            for (int n = 0; n < 4; ++n)
                acc[m][n] = __builtin_amdgcn_mfma_f32_16x16x32_bf16(a[m], b[n], acc[m][n], 0, 0, 0);
    }

    #pragma unroll
    for (int m = 0; m < 4; ++m) {
        #pragma unroll
        for (int n = 0; n < 4; ++n) {
            #pragma unroll
            for (int r = 0; r < 4; ++r) {
                const int row_l = wr * 64 + m * 16 + kg * 4 + r;
                const int col_l = wc * 64 + n * 16 + fr;
                const float g  = acc[m][n][r];
                float sq = rn[row_l] + cn[col_l] - 2.0f * g;
                sq = fmaxf(sq, 0.0f);
                float dv = sqrtf(sq);
                const int grow = rowBase + row_l;
                const int gcol = colBase + col_l;
                if (grow == gcol) dv = 0.0f;
                out[(size_t)grow * NN + gcol] = dv;
            }
        }
    }
}

extern "C" void kernel_launch(void* const* d_in, const int* in_sizes, int n_in,
                              void* d_out, int out_size, void* d_ws, size_t ws_size,
                              hipStream_t stream) {
    const float* X = (const float*)d_in[0];
    float* out = (float*)d_out;

    const size_t xb_bytes   = (size_t)NN * DD * sizeof(unsigned short); // 1 MiB
    const size_t norm_bytes = (size_t)NN * sizeof(float);               // 32 KiB

    if (ws_size >= xb_bytes + norm_bytes) {
        unsigned short* Xb = (unsigned short*)d_ws;
        float* norms = (float*)((char*)d_ws + xb_bytes);
        rips_setup<<<dim3(NN * 8 / 256, 1, 1), dim3(256, 1, 1), 0, stream>>>(X, Xb, norms);
        dim3 grid(NN / 128, NN / 128, 1);
        rips_main<<<grid, dim3(256, 1, 1), 0, stream>>>(Xb, norms, out);
    } else {
        dim3 grid(NN / 128, NN / 128, 1);
        rips_fallback<<<grid, dim3(256, 1, 1), 0, stream>>>(X, out);
    }
}